// Round 8
// baseline (595.058 us; speedup 1.0000x reference)
//
#include <hip/hip_runtime.h>

typedef unsigned short u16;
typedef __attribute__((ext_vector_type(8))) short s16x8;
typedef __attribute__((ext_vector_type(4))) float f32x4;

__device__ __forceinline__ float bf2f(u16 u) {
    union { unsigned int u; float f; } v; v.u = ((unsigned int)u) << 16; return v.f;
}
__device__ __forceinline__ u16 f2bf(float f) {
    union { float f; unsigned int u; } v; v.f = f;
    unsigned int r = v.u + 0x7FFFu + ((v.u >> 16) & 1u);
    return (u16)(r >> 16);
}

// async 16B/lane global->LDS copy. lds base must be wave-uniform; HW writes
// lane l's 16 bytes at base + l*16.
__device__ __forceinline__ void async16(const u16* g, u16* l) {
    __builtin_amdgcn_global_load_lds(
        (const __attribute__((address_space(1))) void*)g,
        (__attribute__((address_space(3))) void*)l,
        16, 0, 0);
}

// ---------------------------------------------------------------------------
// Detect input dtype. flag=1 -> fp32 inputs, flag=0 -> bf16 inputs.
// ---------------------------------------------------------------------------
__global__ __launch_bounds__(256) void detect_dtype(const u16* __restrict__ x,
                                                    int* __restrict__ flag) {
    const int t = threadIdx.x;
    float mx = 0.f;
    #pragma unroll
    for (int j = 0; j < 16; ++j) mx = fmaxf(mx, fabsf(bf2f(x[t * 16 + j])));
    #pragma unroll
    for (int off = 32; off; off >>= 1) mx = fmaxf(mx, __shfl_down(mx, off));
    __shared__ float red[4];
    const int lane = t & 63, wave = t >> 6;
    if (lane == 0) red[wave] = mx;
    __syncthreads();
    if (t == 0) {
        float m = fmaxf(fmaxf(red[0], red[1]), fmaxf(red[2], red[3]));
        *flag = (m > 1e4f) ? 1 : 0;
    }
}

// ---------------------------------------------------------------------------
// Fused per-row int8 fake-quantization for ALL four weight tensors.
// Row map: [0,2048) w_in L=1024 | [2048,3072) w_o L=1024 |
//          [3072,5120) w_mi L=1024 | [5120,6144) w_mo L=2048.
// Vectorized loads (float4 / ushort4); 4 or 8 elems per thread.
// ---------------------------------------------------------------------------
__global__ __launch_bounds__(256) void quant_all(const void* __restrict__ w_in,
                                                 const void* __restrict__ w_o,
                                                 const void* __restrict__ w_mi,
                                                 const void* __restrict__ w_mo,
                                                 u16* __restrict__ qa, u16* __restrict__ qb,
                                                 u16* __restrict__ qc, u16* __restrict__ qd,
                                                 const int* __restrict__ flagp) {
    const int f32 = *flagp;
    const int r = blockIdx.x;
    const void* src; u16* dst; int L, row;
    if (r < 2048)      { src = w_in; dst = qa; L = 1024; row = r; }
    else if (r < 3072) { src = w_o;  dst = qb; L = 1024; row = r - 2048; }
    else if (r < 5120) { src = w_mi; dst = qc; L = 1024; row = r - 3072; }
    else               { src = w_mo; dst = qd; L = 2048; row = r - 5120; }
    const int t = threadIdx.x;
    const int ng = L >> 10;                 // 1 or 2 groups of 4 elems/thread
    float v[8];
    #pragma unroll 2
    for (int g = 0; g < ng; ++g) {
        if (f32) {
            float4 vv = ((const float4*)src)[(size_t)row * (L >> 2) + g * 256 + t];
            v[g*4+0] = vv.x; v[g*4+1] = vv.y; v[g*4+2] = vv.z; v[g*4+3] = vv.w;
        } else {
            ushort4 vv = *(const ushort4*)((const u16*)src + (size_t)row * L + g * 1024 + t * 4);
            v[g*4+0] = bf2f(vv.x); v[g*4+1] = bf2f(vv.y);
            v[g*4+2] = bf2f(vv.z); v[g*4+3] = bf2f(vv.w);
        }
    }
    float mx = 0.f;
    for (int j = 0; j < 4 * ng; ++j) mx = fmaxf(mx, fabsf(v[j]));
    #pragma unroll
    for (int off = 32; off; off >>= 1) mx = fmaxf(mx, __shfl_down(mx, off));
    __shared__ float red[4];
    __shared__ float s_scale;
    const int lane = t & 63, wave = t >> 6;
    if (lane == 0) red[wave] = mx;
    __syncthreads();
    if (t == 0) {
        float m = fmaxf(fmaxf(red[0], red[1]), fmaxf(red[2], red[3]));
        s_scale = fmaxf(m / 127.f, 1e-8f);
    }
    __syncthreads();
    const float scale = s_scale;
    #pragma unroll 2
    for (int g = 0; g < ng; ++g) {
        ushort4 o;
        o.x = f2bf(rintf(v[g*4+0] / scale) * scale);
        o.y = f2bf(rintf(v[g*4+1] / scale) * scale);
        o.z = f2bf(rintf(v[g*4+2] / scale) * scale);
        o.w = f2bf(rintf(v[g*4+3] / scale) * scale);
        *(ushort4*)(dst + (size_t)row * L + g * 1024 + t * 4) = o;
    }
}

// ---------------------------------------------------------------------------
// RMSNorm, wave-per-row (4 rows / 256-thread block): no LDS, no barriers.
// Lane owns elems {q*256 + lane*4 + j : q<4, j<4} (position-consistent
// across f32/bf16 paths). Full 64-lane butterfly gives rs to every lane.
// ---------------------------------------------------------------------------
template <int IN_RAW>
__global__ __launch_bounds__(256) void rmsnorm_w(const void* __restrict__ x,
                                                 const void* __restrict__ w,
                                                 u16* __restrict__ out,
                                                 const int* __restrict__ flagp) {
    const int f32 = *flagp;
    const int lane = threadIdx.x & 63;
    const int row = blockIdx.x * 4 + (threadIdx.x >> 6);
    float xv[16];
    if (IN_RAW && f32) {
        const float4* xp = (const float4*)x + (size_t)row * 256;
        #pragma unroll
        for (int q = 0; q < 4; ++q) {
            float4 vv = xp[q * 64 + lane];
            xv[q*4+0] = vv.x; xv[q*4+1] = vv.y; xv[q*4+2] = vv.z; xv[q*4+3] = vv.w;
        }
    } else {
        const u16* xp = (const u16*)x + (size_t)row * 1024;
        #pragma unroll
        for (int q = 0; q < 4; ++q) {
            ushort4 vv = *(const ushort4*)(xp + q * 256 + lane * 4);
            xv[q*4+0] = bf2f(vv.x); xv[q*4+1] = bf2f(vv.y);
            xv[q*4+2] = bf2f(vv.z); xv[q*4+3] = bf2f(vv.w);
        }
    }
    float s = 0.f;
    #pragma unroll
    for (int j = 0; j < 16; ++j) s += xv[j] * xv[j];
    #pragma unroll
    for (int off = 32; off; off >>= 1) s += __shfl_xor(s, off);
    const float rs = 1.0f / sqrtf(s * (1.0f / 1024.0f) + 1e-6f);
    float wv[16];
    if (f32) {
        const float4* wp = (const float4*)w;
        #pragma unroll
        for (int q = 0; q < 4; ++q) {
            float4 vv = wp[q * 64 + lane];
            wv[q*4+0] = vv.x; wv[q*4+1] = vv.y; wv[q*4+2] = vv.z; wv[q*4+3] = vv.w;
        }
    } else {
        const u16* wp = (const u16*)w;
        #pragma unroll
        for (int q = 0; q < 4; ++q) {
            ushort4 vv = *(const ushort4*)(wp + q * 256 + lane * 4);
            wv[q*4+0] = bf2f(vv.x); wv[q*4+1] = bf2f(vv.y);
            wv[q*4+2] = bf2f(vv.z); wv[q*4+3] = bf2f(vv.w);
        }
    }
    u16* op = out + (size_t)row * 1024;
    #pragma unroll
    for (int q = 0; q < 4; ++q) {
        ushort4 o;
        o.x = f2bf(bf2f(f2bf(xv[q*4+0] * rs)) * wv[q*4+0]);
        o.y = f2bf(bf2f(f2bf(xv[q*4+1] * rs)) * wv[q*4+1]);
        o.z = f2bf(bf2f(f2bf(xv[q*4+2] * rs)) * wv[q*4+2]);
        o.w = f2bf(bf2f(f2bf(xv[q*4+3] * rs)) * wv[q*4+3]);
        *(ushort4*)(op + q * 256 + lane * 4) = o;
    }
}

// ---------------------------------------------------------------------------
// Causal geometric-filter scan + SiLU gate, in-place into the gate half.
// 2 adjacent columns per thread via u32 loads (256 B/wave/step).
// ---------------------------------------------------------------------------
__global__ __launch_bounds__(256) void scan_silu(u16* __restrict__ qkv) {
    const int cp = blockIdx.x * 256 + threadIdx.x;  // col-pair 0..511
    const int chunk = blockIdx.y;                   // 0..15
    const int b = blockIdx.z;                       // 0..3
    const int t0 = chunk * 256;
    const int ts = (t0 >= 256) ? (t0 - 256) : 0;    // r^256 ~ 7e-12
    const float r = 0.90483741803595957f;           // exp(-0.1)
    u16* base = qkv + (size_t)b * 4096 * 2048 + cp * 2;
    float y0 = 0.f, y1 = 0.f;
    #pragma unroll 4
    for (int tt = ts; tt < t0; ++tt) {
        unsigned int sv = *(const unsigned int*)(base + (size_t)tt * 2048);
        y0 = y0 * r + bf2f((u16)sv);
        y1 = y1 * r + bf2f((u16)(sv >> 16));
    }
    #pragma unroll 2
    for (int tt = t0; tt < t0 + 256; ++tt) {
        u16* p = base + (size_t)tt * 2048;
        unsigned int sv = *(const unsigned int*)p;
        unsigned int gv = *(const unsigned int*)(p + 1024);
        y0 = y0 * r + bf2f((u16)sv);
        y1 = y1 * r + bf2f((u16)(sv >> 16));
        float g0 = bf2f((u16)gv), g1 = bf2f((u16)(gv >> 16));
        float e0 = exp2f(-1.442695040888963f * g0);
        float e1 = exp2f(-1.442695040888963f * g1);
        float o0 = y0 * (g0 / (1.f + e0));
        float o1 = y1 * (g1 / (1.f + e1));
        *(unsigned int*)(p + 1024) = (unsigned int)f2bf(o0) | ((unsigned int)f2bf(o1) << 16);
    }
}

// ---------------------------------------------------------------------------
// 256x256 bf16 MFMA GEMM, OVERLAPPED regions: C = A(MxK,lda)@B(NxK)^T [+epi]
// EPI: 0 = none, 1 = add RES, 2 = exact GELU
// BYTE-IDENTICAL to round-7 (passed, absmax 0.03125, 115-117us/dispatch).
// R1/R4/R6/R7 proved the 17.3k cyc/iter plateau is schedule-invariant at
// this geometry (2 waves/SIMD: acc=128 AGPR + 128 VGPR caps occupancy);
// GEMM frozen pending disasm-level evidence. This round targets non-GEMM.
// ---------------------------------------------------------------------------
#define BAR __builtin_amdgcn_s_barrier()
#define PRIO1 __builtin_amdgcn_s_setprio(1)
#define PRIO0 __builtin_amdgcn_s_setprio(0)
#define STAGE_A(BUF, HALF, KOFF) do { \
    async16(Ag + (size_t)((HALF) * 128) * lda + (KOFF), AsW[BUF] + (HALF) * 8192); \
    async16(Ag + (size_t)((HALF) * 128 + 64) * lda + (KOFF), AsW[BUF] + (HALF) * 8192 + 4096); \
} while (0)
#define STAGE_B(BUF, HALF, KOFF) do { \
    async16(Bg + (size_t)((HALF) * 128) * K + (KOFF), BsW[BUF] + (HALF) * 8192); \
    async16(Bg + (size_t)((HALF) * 128 + 64) * K + (KOFF), BsW[BUF] + (HALF) * 8192 + 4096); \
} while (0)
#define LOAD_A(BUF, MH) do { \
    _Pragma("unroll") \
    for (int fm = 0; fm < 4; ++fm) { \
        af[fm][0] = *(const s16x8*)&As[BUF][aBase + ((MH) * 64 + fm * 16) * 64 + sc0]; \
        af[fm][1] = *(const s16x8*)&As[BUF][aBase + ((MH) * 64 + fm * 16) * 64 + sc1]; \
    } \
} while (0)
#define LOAD_B(BUF, NH, DST) do { \
    _Pragma("unroll") \
    for (int fn = 0; fn < 2; ++fn) { \
        DST[fn][0] = *(const s16x8*)&Bs[BUF][bBase + ((NH) * 32 + fn * 16) * 64 + sc0]; \
        DST[fn][1] = *(const s16x8*)&Bs[BUF][bBase + ((NH) * 32 + fn * 16) * 64 + sc1]; \
    } \
} while (0)
#define MFMA16(MH, NH, BF) do { \
    _Pragma("unroll") \
    for (int kh = 0; kh < 2; ++kh) \
        _Pragma("unroll") \
        for (int fm = 0; fm < 4; ++fm) \
            _Pragma("unroll") \
            for (int fn = 0; fn < 2; ++fn) \
                acc[(MH) * 4 + fm][(NH) * 2 + fn] = \
                    __builtin_amdgcn_mfma_f32_16x16x32_bf16( \
                        af[fm][kh], BF[fn][kh], acc[(MH) * 4 + fm][(NH) * 2 + fn], 0, 0, 0); \
} while (0)

template <int EPI>
__global__ __launch_bounds__(512, 2) void gemm256(const u16* __restrict__ A, int lda,
                                                  const u16* __restrict__ B,
                                                  const void* __restrict__ RES, int res_raw,
                                                  void* __restrict__ C, int c_raw,
                                                  int M, int N, int K,
                                                  const int* __restrict__ flagp) {
    const int f32 = *flagp;
    asm volatile("" :: "s"(f32));   // force flag load before staging
    __shared__ u16 As[2][256 * 64];
    __shared__ u16 Bs[2][256 * 64];
    const int t = threadIdx.x;
    const int lane = t & 63, wave = t >> 6;
    const int wm = wave >> 2, wn = wave & 3;       // 2 x 4 wave grid
    const int lr = lane & 15, quad = lane >> 4;

    // bijective XCD-chunked swizzle (grid is always a multiple of 8).
    const int NT = N >> 8;
    const int d = blockIdx.x;
    const int sw = (d & 7) * ((int)gridDim.x >> 3) + (d >> 3);
    const int m0 = (sw / NT) * 256;
    const int n0 = (sw % NT) * 256;

    // staging: thread t covers LDS slot (row = 64*i + t>>3, chunk = t&7);
    // source pre-swizzled: logical chunk = (t&7) ^ ((t>>3)&7).
    const int trow = t >> 3;
    const int tco = ((t & 7) ^ (trow & 7)) * 8;
    const u16* Ag = A + (size_t)(m0 + trow) * lda + tco;
    const u16* Bg = B + (size_t)(n0 + trow) * K + tco;
    u16* const AsW[2] = { &As[0][wave * 512], &As[1][wave * 512] };
    u16* const BsW[2] = { &Bs[0][wave * 512], &Bs[1][wave * 512] };

    // reader offsets: stored chunk = (kh*4 + quad) ^ (lr&7)
    const int aBase = (wm * 128 + lr) * 64;
    const int bBase = (wn * 64 + lr) * 64;
    const int sc0 = (quad ^ (lr & 7)) * 8;
    const int sc1 = ((4 + quad) ^ (lr & 7)) * 8;

    f32x4 acc[8][4];
    #pragma unroll
    for (int i = 0; i < 8; ++i)
        #pragma unroll
        for (int j = 0; j < 4; ++j) acc[i][j] = (f32x4){0.f, 0.f, 0.f, 0.f};
    s16x8 af[4][2], b0[2][2], b1[2][2];

    // prologue: tile0 (8 loads) + B(T1) (4 loads); vmcnt(4) retires tile0,
    // leaves invariant {B(T1):4} outstanding.
    STAGE_A(0, 0, 0); STAGE_A(0, 1, 0);
    STAGE_B(0, 0, 0); STAGE_B(0, 1, 0);
    STAGE_B(1, 0, 64); STAGE_B(1, 1, 64);
    asm volatile("s_waitcnt vmcnt(4)");
    BAR;

    const int NIT = K >> 7;          // K / 128 (two 64-wide K-tiles per iter)
    for (int it = 0; it < NIT - 1; ++it) {
        const int kc = it << 7;
        // ---- Q1: tile T (buf0), C-half mh0 ----
        STAGE_A(1, 0, kc + 64); STAGE_A(1, 1, kc + 64);
        LOAD_A(0, 0); LOAD_B(0, 0, b0); LOAD_B(0, 1, b1);
        PRIO1; MFMA16(0, 0, b0); MFMA16(0, 1, b1); PRIO0;
        BAR;
        // ---- Q2: tile T (buf0), C-half mh1 ----
        STAGE_B(0, 0, kc + 128); STAGE_B(0, 1, kc + 128);
        LOAD_A(0, 1);
        asm volatile("s_waitcnt vmcnt(4)");                 // retires tile T+1
        PRIO1; MFMA16(1, 1, b1); MFMA16(1, 0, b0); PRIO0;
        BAR;
        // ---- Q3: tile T+1 (buf1), C-half mh0 ----
        STAGE_A(0, 0, kc + 128); STAGE_A(0, 1, kc + 128);
        LOAD_A(1, 0); LOAD_B(1, 0, b0); LOAD_B(1, 1, b1);
        PRIO1; MFMA16(0, 0, b0); MFMA16(0, 1, b1); PRIO0;
        BAR;
        // ---- Q4: tile T+1 (buf1), C-half mh1 ----
        STAGE_B(1, 0, kc + 192); STAGE_B(1, 1, kc + 192);
        LOAD_A(1, 1);
        asm volatile("s_waitcnt vmcnt(4)");                 // retires tile T+2
        PRIO1; MFMA16(1, 1, b1); MFMA16(1, 0, b0); PRIO0;
        BAR;
    }
    {   // last iteration: stage A(T+1) at LQ1; vmcnt(0) at LQ2; no more stages
        const int kc = (NIT - 1) << 7;
        STAGE_A(1, 0, kc + 64); STAGE_A(1, 1, kc + 64);
        LOAD_A(0, 0); LOAD_B(0, 0, b0); LOAD_B(0, 1, b1);
        PRIO1; MFMA16(0, 0, b0); MFMA16(0, 1, b1); PRIO0;
        BAR;
        LOAD_A(0, 1);
        asm volatile("s_waitcnt vmcnt(0)");                 // drain B+A of T+1
        PRIO1; MFMA16(1, 1, b1); MFMA16(1, 0, b0); PRIO0;
        BAR;
        LOAD_A(1, 0); LOAD_B(1, 0, b0); LOAD_B(1, 1, b1);
        PRIO1; MFMA16(0, 0, b0); MFMA16(0, 1, b1); PRIO0;
        BAR;
        LOAD_A(1, 1);
        PRIO1; MFMA16(1, 1, b1); MFMA16(1, 0, b0); PRIO0;
    }

    // epilogue: C/D layout col=lane&15, row=quad*4+reg (verified mapping)
    #pragma unroll
    for (int i = 0; i < 8; ++i) {
        const int mh = i >> 2, fm = i & 3;
        #pragma unroll
        for (int j = 0; j < 4; ++j) {
            const int nh = j >> 1, fn = j & 1;
            #pragma unroll
            for (int r = 0; r < 4; ++r) {
                int gm = m0 + wm * 128 + mh * 64 + fm * 16 + quad * 4 + r;
                int gn = n0 + wn * 64 + nh * 32 + fn * 16 + lr;
                size_t idx = (size_t)gm * N + gn;
                float v = acc[i][j][r];
                if (EPI == 1) {
                    float rv = (res_raw && f32) ? ((const float*)RES)[idx]
                                                : bf2f(((const u16*)RES)[idx]);
                    v += rv;
                }
                if (EPI == 2) v = 0.5f * v * (1.0f + erff(v * 0.70710678118654752f));
                if (c_raw && f32) ((float*)C)[idx] = v;
                else              ((u16*)C)[idx] = f2bf(v);
            }
        }
    }
}

// ---------------------------------------------------------------------------
extern "C" void kernel_launch(void* const* d_in, const int* in_sizes, int n_in,
                              void* d_out, int out_size, void* d_ws, size_t ws_size,
                              hipStream_t stream) {
    const void* x    = d_in[0];   // (4,4096,1024)  fp32 or bf16
    const void* n1w  = d_in[1];   // (1024,)
    const void* n2w  = d_in[2];   // (1024,)
    const void* w_in = d_in[3];   // (2048,1024)
    const void* w_o  = d_in[4];   // (1024,1024)
    const void* w_mi = d_in[5];   // (2048,1024)
    const void* w_mo = d_in[6];   // (1024,2048)
    // d_in[7] fixed_filter: exp(-0.1*t) geometric -> IIR scan, unused

    char* ws = (char*)d_ws;
    int* flag  = (int*)(ws + 0);                 // 256 B reserved
    u16* wq_in = (u16*)(ws + 256);               // 4 MB
    u16* wq_o  = (u16*)(ws + 256 + 4194304);     // 2 MB
    u16* wq_mi = (u16*)(ws + 256 + 6291456);     // 4 MB
    u16* wq_mo = (u16*)(ws + 256 + 10485760);    // 4 MB
    u16* hbuf  = (u16*)(ws + 256 + 14680064);    // 32 MB (h / h2, bf16)
    u16* qkv   = (u16*)(ws + 256 + 48234496);    // 64 MB (qkv / m, bf16)
    u16* x2b   = (u16*)(ws + 256 + 115343360);   // 32 MB (x2, bf16)

    detect_dtype<<<1, 256, 0, stream>>>((const u16*)x, flag);

    // all 4 weight fake-quants in one launch (was 4)
    quant_all<<<6144, 256, 0, stream>>>(w_in, w_o, w_mi, w_mo,
                                        wq_in, wq_o, wq_mi, wq_mo, flag);

    // h = rmsnorm(x, n1w)   (wave-per-row, 4 rows/block)
    rmsnorm_w<1><<<4096, 256, 0, stream>>>(x, n1w, hbuf, flag);
    // qkv = h @ wq_in^T   (16384 x 2048), grid 64x8 = 512
    gemm256<0><<<512, 512, 0, stream>>>(hbuf, 1024, wq_in,
                                        nullptr, 0, qkv, 0,
                                        16384, 2048, 1024, flag);
    // gate half of qkv <- causal-conv(signal) * silu(gate), in place
    scan_silu<<<dim3(2, 16, 4), 256, 0, stream>>>(qkv);
    // x2 = x + attn @ wq_o^T   (16384 x 1024), grid 64x4 = 256
    gemm256<1><<<256, 512, 0, stream>>>(qkv + 1024, 2048, wq_o,
                                        x, 1, x2b, 0,
                                        16384, 1024, 1024, flag);
    // h2 = rmsnorm(x2, n2w)
    rmsnorm_w<0><<<4096, 256, 0, stream>>>(x2b, n2w, hbuf, flag);
    // m = gelu(h2 @ wq_mi^T)  (16384 x 2048), overwrite qkv
    gemm256<2><<<512, 512, 0, stream>>>(hbuf, 1024, wq_mi,
                                        nullptr, 0, qkv, 0,
                                        16384, 2048, 1024, flag);
    // out = x2 + m @ wq_mo^T  -> d_out in the detected dtype (K=2048)
    gemm256<1><<<256, 512, 0, stream>>>(qkv, 2048, wq_mo,
                                        x2b, 0, d_out, 1,
                                        16384, 1024, 2048, flag);
}